// Round 5
// baseline (531.407 us; speedup 1.0000x reference)
//
#include <hip/hip_runtime.h>

typedef _Float16 half_t;
typedef _Float16 half4 __attribute__((ext_vector_type(4)));
typedef _Float16 half8 __attribute__((ext_vector_type(8)));
typedef float floatx4 __attribute__((ext_vector_type(4)));

#define HST 264            // LDS row stride in halves: 256 + 8 pad
#define B_ 32
#define T_ 512
#define H_ 256
#define L_ 2048

// ------------------------------------------------------------------
// Weight prep: fp32 [pred][layer][k][n] -> f16 MFMA fragment layout.
// Frag id t = ((pred*4+layer)*8 + kk)*16 + nt ; lane l holds 8 halves:
//   W[kk*32 + (l>>4)*8 + j][nt*16 + (l&15)]
// (A-operand layout for the swapped D = W^T * h^T formulation)
// ------------------------------------------------------------------
__global__ void prep_weights_kernel(const float* __restrict__ dur_W,
                                    const float* __restrict__ pit_W,
                                    const float* __restrict__ en_W,
                                    half_t* __restrict__ Wp) {
  int g = blockIdx.x * 256 + threadIdx.x;   // [0, 98304)
  int lane = g & 63;
  int t = g >> 6;                           // [0, 1536)
  int nt = t & 15;
  int kk = (t >> 4) & 7;
  int layer = (t >> 7) & 3;
  int pred = t >> 9;
  const float* W = (pred == 0 ? dur_W : (pred == 1 ? pit_W : en_W)) + layer * 65536;
  int n = nt * 16 + (lane & 15);
  int k0 = kk * 32 + (lane >> 4) * 8;
  half8 o;
#pragma unroll
  for (int j = 0; j < 8; ++j) o[j] = (half_t)W[(k0 + j) * 256 + n];
  *(half8*)&Wp[(size_t)t * 512 + lane * 8] = o;
}

// ------------------------------------------------------------------
// Mega kernel: length-regulate + out0/out4/out5 + all three 4-layer
// MLP predictors, one dispatch.
//   blocks [0,1024): pitch (mode 1)  -- also scan + out0 + out5 + out4
//   blocks [1024,2048): energy (mode 2) -- scan for own gather only
//   blocks [2048,2304): duration (mode 0)
// Block = 128 threads (2 waves) owning 64 rows. Waves split N
// (wave w computes nt = w*8..w*8+7) -> block reads each layer's
// weights once from L2. All 64 rows' h fragments register-resident
// (hf = 128 VGPR); W double-buffered (64 VGPR). ~230 VGPR payload
// fits the 256-cap of launch_bounds(128) -> no spill, and total
// regs/wave <= 256 -> 2 waves/SIMD; LDS 35.8KB -> 4 blocks/CU.
// Swapped MFMA (A=W, B=h): D[n][m] -> lane holds 4 consecutive
// features of one token -> packed half4 LDS writes; B-fragment of
// h^T is bit-identical to the A-fragment of h.
// ------------------------------------------------------------------
__global__ __launch_bounds__(128) void mega_kernel(
    const float* __restrict__ x,
    const half_t* __restrict__ Wp,
    const int* __restrict__ durt,
    const float* __restrict__ pitch_t, const float* __restrict__ energy_t,
    const float* __restrict__ pemb, const float* __restrict__ eemb,
    const float* __restrict__ dur_b, const float* __restrict__ dur_w, const float* __restrict__ dur_b2,
    const float* __restrict__ pit_b, const float* __restrict__ pit_w, const float* __restrict__ pit_b2,
    const float* __restrict__ en_b,  const float* __restrict__ en_w,  const float* __restrict__ en_b2,
    const float* __restrict__ src_seq, const unsigned char* __restrict__ src_mask,
    float* __restrict__ out0, float* __restrict__ out1, float* __restrict__ out2,
    float* __restrict__ out3, float* __restrict__ out4, float* __restrict__ out5) {
  __shared__ half_t hlds[64 * HST];
  __shared__ int cum_l[T_];

  int bid = blockIdx.x;
  int mode, blk;
  const half_t* W; const float* bias; const float* wh; const float* b2p; float* outp;
  if (bid < 1024)      { mode = 1; blk = bid;        W = Wp + 262144; bias = pit_b; wh = pit_w; b2p = pit_b2; outp = out2; }
  else if (bid < 2048) { mode = 2; blk = bid - 1024; W = Wp + 524288; bias = en_b;  wh = en_w;  b2p = en_b2;  outp = out3; }
  else                 { mode = 0; blk = bid - 2048; W = Wp;          bias = dur_b; wh = dur_w; b2p = dur_b2; outp = out1; }

  int tid = threadIdx.x;
  int wv = tid >> 6, lane = tid & 63;
  int mi = lane & 15, qi = lane >> 4;
  int brow0 = blk * 64;

  // ---- stage 64 input rows (f16) into LDS; wave stages its 32 rows ----
  if (mode == 0) {
    for (int it = 0; it < 32; ++it) {
      int rl = wv * 32 + it;
      const float4 xv = *(const float4*)&x[(size_t)(brow0 + rl) * H_ + lane * 4];
      half4 h4;
      h4[0] = (half_t)xv.x; h4[1] = (half_t)xv.y;
      h4[2] = (half_t)xv.z; h4[3] = (half_t)xv.w;
      *(half4*)&hlds[rl * HST + lane * 4] = h4;
    }
  } else {
    int b = brow0 >> 11;                 // 64 | 2048, frames per batch
    int m0 = brow0 & (L_ - 1);
    // -- in-wave scan of this batch's durations (each wave redundantly) --
    {
      const int* dr = durt + b * T_;
      int v[8];
      int base = lane * 8;
#pragma unroll
      for (int j = 0; j < 8; ++j) v[j] = dr[base + j];
#pragma unroll
      for (int j = 1; j < 8; ++j) v[j] += v[j - 1];
      int tot = v[7];
      int inc = tot;
      for (int d = 1; d < 64; d <<= 1) {
        int t = __shfl_up(inc, d);
        if (lane >= d) inc += t;
      }
      int excl = inc - tot;
#pragma unroll
      for (int j = 0; j < 8; ++j) cum_l[base + j] = excl + v[j];
    }
    int ml = min(__shfl((int)0, 0) + 0, 0);  // placeholder, replaced below
    {
      // total = inclusive scan at lane 63
      int t63 = cum_l[T_ - 1];             // same value both waves wrote
      ml = min(t63, L_);
    }
    // -- per-lane meta for this wave's 32 frames (lanes 0..31) --
    int idxr = 0, pir = 0, eir = 0;
    if (lane < 32) {
      int m = m0 + wv * 32 + lane;
      int lo = 0;
#pragma unroll
      for (int sh = 8; sh >= 0; --sh) {
        int c = lo + (1 << sh);
        if (c <= T_ && cum_l[c - 1] <= m) lo = c;
      }
      idxr = min(lo, T_ - 1);
      if (mode == 1) {
        int g = b * L_ + m;
        pir = (int)ceilf(pitch_t[g] * 256.0f);
        eir = (int)ceilf(energy_t[g] * 256.0f);
        out5[g] = (m >= ml) ? 1.0f : 0.0f;
        if (m == 0 && lane == 0) out4[b] = (float)ml;
      }
    }
    // -- staging gather (+ fused out0 for mode 1) --
    for (int it = 0; it < 32; ++it) {
      int rl = wv * 32 + it;
      int m = m0 + rl;
      int ir = __shfl(idxr, it);
      float4 xv = {0.f, 0.f, 0.f, 0.f};
      if (m < ml) xv = *(const float4*)&x[((size_t)(b * T_ + ir)) * H_ + lane * 4];
      if (mode == 1) {
        int pi = __shfl(pir, it);
        int ei = __shfl(eir, it);
        const float4 pv = *(const float4*)&pemb[(size_t)pi * H_ + lane * 4];
        const float4 ev = *(const float4*)&eemb[(size_t)ei * H_ + lane * 4];
        float4 o;
        o.x = xv.x + pv.x + ev.x;
        o.y = xv.y + pv.y + ev.y;
        o.z = xv.z + pv.z + ev.z;
        o.w = xv.w + pv.w + ev.w;
        *(float4*)&out0[((size_t)(b * L_ + m)) * H_ + lane * 4] = o;
      }
      half4 h4;
      h4[0] = (half_t)xv.x; h4[1] = (half_t)xv.y;
      h4[2] = (half_t)xv.z; h4[3] = (half_t)xv.w;
      *(half4*)&hlds[rl * HST + lane * 4] = h4;
    }
  }
  __syncthreads();

  // ---- 4 layers: h = relu(h @ W + b) ----
  int nt0 = wv * 8;
#pragma unroll 1
  for (int layer = 0; layer < 4; ++layer) {
    // all 64 rows' fragments into registers (128 VGPRs)
    half8 hf[4][8];   // [mt][kk] : h[mt*16+mi][kk*32+qi*8 .. +7]
#pragma unroll
    for (int mt = 0; mt < 4; ++mt)
#pragma unroll
      for (int kk = 0; kk < 8; ++kk)
        hf[mt][kk] = *(const half8*)&hlds[(mt * 16 + mi) * HST + kk * 32 + qi * 8];
    __syncthreads();   // all reads done before anyone writes this layer

    const half_t* wl = W + (size_t)layer * 65536;
    const float* bl = bias + layer * 256;
    half8 wbuf[2][8];
    float4 bbuf[2];
#pragma unroll
    for (int kk = 0; kk < 8; ++kk)
      wbuf[0][kk] = *(const half8*)&wl[(size_t)(kk * 16 + nt0) * 512 + lane * 8];
    bbuf[0] = *(const float4*)&bl[nt0 * 16 + qi * 4];

#pragma unroll
    for (int ntl = 0; ntl < 8; ++ntl) {
      int cur = ntl & 1, nxt = cur ^ 1;
      if (ntl < 7) {
#pragma unroll
        for (int kk = 0; kk < 8; ++kk)
          wbuf[nxt][kk] = *(const half8*)&wl[(size_t)(kk * 16 + nt0 + ntl + 1) * 512 + lane * 8];
        bbuf[nxt] = *(const float4*)&bl[(nt0 + ntl + 1) * 16 + qi * 4];
      }
      floatx4 acc[4];
#pragma unroll
      for (int mt = 0; mt < 4; ++mt)
        acc[mt] = (floatx4){bbuf[cur].x, bbuf[cur].y, bbuf[cur].z, bbuf[cur].w};
#pragma unroll
      for (int kk = 0; kk < 8; ++kk)
#pragma unroll
        for (int mt = 0; mt < 4; ++mt)
          acc[mt] = __builtin_amdgcn_mfma_f32_16x16x32_f16(wbuf[cur][kk], hf[mt][kk], acc[mt], 0, 0, 0);
      int colbase = (nt0 + ntl) * 16 + qi * 4;
#pragma unroll
      for (int mt = 0; mt < 4; ++mt) {
        half4 h4;
        h4[0] = (half_t)fmaxf(acc[mt][0], 0.f);
        h4[1] = (half_t)fmaxf(acc[mt][1], 0.f);
        h4[2] = (half_t)fmaxf(acc[mt][2], 0.f);
        h4[3] = (half_t)fmaxf(acc[mt][3], 0.f);
        *(half4*)&hlds[(mt * 16 + mi) * HST + colbase] = h4;
      }
    }
    __syncthreads();   // writes done before next layer's reads / head
  }

  // ---- head: out = h . w + b2, per-mode epilogue. 2 lanes per row ----
  {
    int r = lane >> 1, hf2 = lane & 1;
    int rl = wv * 32 + r;
    float sum = 0.f;
    const half_t* hrow = &hlds[rl * HST + hf2 * 128];
    const float* whp = wh + hf2 * 128;
#pragma unroll
    for (int j = 0; j < 16; ++j) {
      half8 hv = *(const half8*)&hrow[j * 8];
#pragma unroll
      for (int u = 0; u < 8; ++u) sum += (float)hv[u] * whp[j * 8 + u];
    }
    sum += __shfl_xor(sum, 1);
    if (hf2 == 0) {
      int row = brow0 + rl;
      float d = sum + b2p[0];
      if (mode == 0) {
        if (src_mask[row]) d = 0.f;
        float s2 = src_seq[(size_t)row * 3 + 2];
        outp[row] = (tanhf(d) + 1.0f) * s2;
      } else {
        int b = row >> 11;
        int m = row & (L_ - 1);
        // recompute ml cheaply from LDS cum (still valid? cum_l was
        // overwritten only in mode!=0 path before sync; safe to reload)
        int t63 = cum_l[T_ - 1];
        int ml2 = min(t63, L_);
        float v = (m >= ml2) ? 0.f : d;
        outp[row] = (mode == 1) ? fmaxf(v, 0.f) : v;
      }
    }
  }
}

extern "C" void kernel_launch(void* const* d_in, const int* in_sizes, int n_in,
                              void* d_out, int out_size, void* d_ws, size_t ws_size,
                              hipStream_t stream) {
  const float* x        = (const float*)d_in[0];
  const float* src_seq  = (const float*)d_in[1];
  const int*   durt     = (const int*)d_in[2];
  const float* pitcht   = (const float*)d_in[3];
  const float* energyt  = (const float*)d_in[4];
  const unsigned char* src_mask = (const unsigned char*)d_in[5];
  const float* dur_W  = (const float*)d_in[7];
  const float* dur_b  = (const float*)d_in[8];
  const float* dur_w  = (const float*)d_in[9];
  const float* dur_b2 = (const float*)d_in[10];
  const float* pit_W  = (const float*)d_in[11];
  const float* pit_b  = (const float*)d_in[12];
  const float* pit_w  = (const float*)d_in[13];
  const float* pit_b2 = (const float*)d_in[14];
  const float* en_W   = (const float*)d_in[15];
  const float* en_b   = (const float*)d_in[16];
  const float* en_w   = (const float*)d_in[17];
  const float* en_b2  = (const float*)d_in[18];
  const float* pemb   = (const float*)d_in[19];
  const float* eemb   = (const float*)d_in[20];

  float* out0 = (float*)d_out;              // [32,2048,256]
  float* out1 = out0 + 16777216;            // [32,512]   log_duration
  float* out2 = out1 + 16384;               // [32,2048]  pitch_prediction
  float* out3 = out2 + 65536;               // [32,2048]  energy_prediction
  float* out4 = out3 + 65536;               // [32]       mel_len (as float)
  float* out5 = out4 + 32;                  // [32,2048]  mel_mask (0/1 float)

  half_t* Wp = (half_t*)d_ws;               // 786432 halves = 1.5 MB

  prep_weights_kernel<<<dim3(384), dim3(256), 0, stream>>>(dur_W, pit_W, en_W, Wp);
  mega_kernel<<<dim3(2304), dim3(128), 0, stream>>>(
      x, Wp, durt, pitcht, energyt, pemb, eemb,
      dur_b, dur_w, dur_b2,
      pit_b, pit_w, pit_b2,
      en_b, en_w, en_b2,
      src_seq, src_mask,
      out0, out1, out2, out3, out4, out5);
}

// Round 6
// 250.660 us; speedup vs baseline: 2.1200x; 2.1200x over previous
//
#include <hip/hip_runtime.h>

typedef _Float16 half_t;
typedef _Float16 half4 __attribute__((ext_vector_type(4)));
typedef _Float16 half8 __attribute__((ext_vector_type(8)));
typedef float floatx4 __attribute__((ext_vector_type(4)));

#define HST 264            // LDS row stride in halves: 256 + 8 pad
#define B_ 32
#define T_ 512
#define H_ 256
#define L_ 2048

// ------------------------------------------------------------------
// Weight prep: fp32 [pred][layer][k][n] -> f16 MFMA fragment layout.
// Frag id t = ((pred*4+layer)*8 + kk)*16 + nt ; lane l holds 8 halves:
//   W[kk*32 + (l>>4)*8 + j][nt*16 + (l&15)]
// (A-operand layout for the swapped D = W^T * h^T formulation)
// ------------------------------------------------------------------
__global__ void prep_weights_kernel(const float* __restrict__ dur_W,
                                    const float* __restrict__ pit_W,
                                    const float* __restrict__ en_W,
                                    half_t* __restrict__ Wp) {
  int g = blockIdx.x * 256 + threadIdx.x;   // [0, 98304)
  int lane = g & 63;
  int t = g >> 6;                           // [0, 1536)
  int nt = t & 15;
  int kk = (t >> 4) & 7;
  int layer = (t >> 7) & 3;
  int pred = t >> 9;
  const float* W = (pred == 0 ? dur_W : (pred == 1 ? pit_W : en_W)) + layer * 65536;
  int n = nt * 16 + (lane & 15);
  int k0 = kk * 32 + (lane >> 4) * 8;
  half8 o;
#pragma unroll
  for (int j = 0; j < 8; ++j) o[j] = (half_t)W[(k0 + j) * 256 + n];
  *(half8*)&Wp[(size_t)t * 512 + lane * 8] = o;
}

// ------------------------------------------------------------------
// Meta: per-batch scan of durations, searchsorted idx, pitch/energy
// bucket idx, mel_len (out4), mel_mask (out5).
// Grid 32 batches x 4 chunks of 512 frames, block 256.
// ------------------------------------------------------------------
__global__ void meta_kernel(const int* __restrict__ dur,
                            const float* __restrict__ pitch_t,
                            const float* __restrict__ energy_t,
                            int* __restrict__ idx_ws,
                            int* __restrict__ pi_ws,
                            int* __restrict__ ei_ws,
                            int* __restrict__ ml_ws,
                            float* __restrict__ out4,
                            float* __restrict__ out5) {
  __shared__ int cum_l[T_];
  __shared__ int ml_s;
  int b = blockIdx.x >> 2;
  int chunk = blockIdx.x & 3;
  int tid = threadIdx.x;
  if (tid < 64) {
    int l = tid;
    const int* dr = dur + b * T_;
    int v[8];
    int base = l * 8;
#pragma unroll
    for (int j = 0; j < 8; ++j) v[j] = dr[base + j];
#pragma unroll
    for (int j = 1; j < 8; ++j) v[j] += v[j - 1];
    int tot = v[7];
    int inc = tot;
    for (int d = 1; d < 64; d <<= 1) {
      int t = __shfl_up(inc, d);
      if (l >= d) inc += t;
    }
    int excl = inc - tot;
#pragma unroll
    for (int j = 0; j < 8; ++j) cum_l[base + j] = excl + v[j];
    if (l == 63) {
      int mel = min(inc, L_);
      ml_s = mel;
      if (chunk == 0) {
        ml_ws[b] = mel;
        out4[b] = (float)mel;
      }
    }
  }
  __syncthreads();
  int ml = ml_s;
#pragma unroll
  for (int j = 0; j < 2; ++j) {
    int m = chunk * 512 + j * 256 + tid;
    int lo = 0;
#pragma unroll
    for (int sh = 8; sh >= 0; --sh) {
      int c = lo + (1 << sh);
      if (c <= T_ && cum_l[c - 1] <= m) lo = c;
    }
    int idx = min(lo, T_ - 1);
    int g = b * L_ + m;
    idx_ws[g] = idx;
    pi_ws[g] = (int)ceilf(pitch_t[g] * 256.0f);
    ei_ws[g] = (int)ceilf(energy_t[g] * 256.0f);
    out5[g] = (m >= ml) ? 1.0f : 0.0f;
  }
}

// ------------------------------------------------------------------
// out0 = gather(x, idx) * inbounds + pemb[pi] + eemb[ei].
// One frame per wave, 4 waves/block, 16384 blocks.
// ------------------------------------------------------------------
__global__ void out0_kernel(const float* __restrict__ x,
                            const float* __restrict__ pemb,
                            const float* __restrict__ eemb,
                            const int* __restrict__ idx_ws,
                            const int* __restrict__ pi_ws,
                            const int* __restrict__ ei_ws,
                            const int* __restrict__ ml_ws,
                            float* __restrict__ out0) {
  int wid = blockIdx.x * 4 + (threadIdx.x >> 6);   // frame id [0, 65536)
  int lane = threadIdx.x & 63;
  int b = wid >> 11;
  int m = wid & (L_ - 1);
  int ml = ml_ws[b];
  int ir = idx_ws[wid];
  int pi = pi_ws[wid];
  int ei = ei_ws[wid];
  float4 xv = {0.f, 0.f, 0.f, 0.f};
  if (m < ml) xv = *(const float4*)&x[((size_t)(b * T_ + ir)) * H_ + lane * 4];
  const float4 pv = *(const float4*)&pemb[(size_t)pi * H_ + lane * 4];
  const float4 ev = *(const float4*)&eemb[(size_t)ei * H_ + lane * 4];
  float4 o;
  o.x = xv.x + pv.x + ev.x;
  o.y = xv.y + pv.y + ev.y;
  o.z = xv.z + pv.z + ev.z;
  o.w = xv.w + pv.w + ev.w;
  *(float4*)&out0[(size_t)wid * H_ + lane * 4] = o;
}

// ------------------------------------------------------------------
// Fused 4-layer MLP + head, all three predictors in one dispatch.
// blocks [0,1024): pitch  [1024,2048): energy  [2048,2304): duration.
// Block = 128 threads (2 waves) owning 64 rows; each wave owns 32
// rows EXCLUSIVELY -> zero __syncthreads (in-place LDS update safe:
// the wave reads its rows' fragments into registers before writing).
// Each wave loops ALL 16 nt tiles (no N-split) with a W ping-pong:
// VGPR ~ hf(64) + wbuf(64) + acc/bias/misc -> ~180, 2 waves/SIMD.
// LDS 33.8 KB -> 4 blocks/CU -> 8 waves/CU.
// Swapped MFMA (A=W, B=h): D[n][m] -> lane holds 4 consecutive
// features of one token -> packed half4 LDS writes; the B-fragment
// of h^T is bit-identical to the A-fragment of h (same LDS reads).
// ------------------------------------------------------------------
__global__ __launch_bounds__(128) void predictor_kernel(
    const float* __restrict__ x,
    const half_t* __restrict__ Wp,
    const float* __restrict__ dur_b, const float* __restrict__ dur_w, const float* __restrict__ dur_b2,
    const float* __restrict__ pit_b, const float* __restrict__ pit_w, const float* __restrict__ pit_b2,
    const float* __restrict__ en_b,  const float* __restrict__ en_w,  const float* __restrict__ en_b2,
    const int* __restrict__ idx_ws, const int* __restrict__ mlw,
    const float* __restrict__ src_seq, const unsigned char* __restrict__ src_mask,
    float* __restrict__ out1, float* __restrict__ out2, float* __restrict__ out3) {
  __shared__ half_t hlds[64 * HST];
  int bid = blockIdx.x;
  int mode, blk;
  const half_t* W; const float* bias; const float* wh; const float* b2p; float* outp;
  if (bid < 1024)      { mode = 1; blk = bid;        W = Wp + 262144; bias = pit_b; wh = pit_w; b2p = pit_b2; outp = out2; }
  else if (bid < 2048) { mode = 2; blk = bid - 1024; W = Wp + 524288; bias = en_b;  wh = en_w;  b2p = en_b2;  outp = out3; }
  else                 { mode = 0; blk = bid - 2048; W = Wp;          bias = dur_b; wh = dur_w; b2p = dur_b2; outp = out1; }

  int tid = threadIdx.x;
  int wv = tid >> 6, lane = tid & 63;
  int mi = lane & 15, qi = lane >> 4;
  int wrow0 = wv * 32;            // wave's exclusive 32 rows within block
  int brow0 = blk * 64;

  // ---- stage this wave's 32 input rows (f16) into LDS ----
  if (mode == 0) {
    for (int it = 0; it < 32; ++it) {
      int rl = wrow0 + it;
      const float4 xv = *(const float4*)&x[(size_t)(brow0 + rl) * H_ + lane * 4];
      half4 h4;
      h4[0] = (half_t)xv.x; h4[1] = (half_t)xv.y;
      h4[2] = (half_t)xv.z; h4[3] = (half_t)xv.w;
      *(half4*)&hlds[rl * HST + lane * 4] = h4;
    }
  } else {
    int b = brow0 >> 11;          // 64 | 2048 frames per batch
    int m0 = brow0 & (L_ - 1);
    int ml = mlw[b];
    for (int it = 0; it < 32; ++it) {
      int rl = wrow0 + it;
      int m = m0 + rl;
      float4 xv = {0.f, 0.f, 0.f, 0.f};
      if (m < ml) {
        int ir = idx_ws[b * L_ + m];
        xv = *(const float4*)&x[((size_t)(b * T_ + ir)) * H_ + lane * 4];
      }
      half4 h4;
      h4[0] = (half_t)xv.x; h4[1] = (half_t)xv.y;
      h4[2] = (half_t)xv.z; h4[3] = (half_t)xv.w;
      *(half4*)&hlds[rl * HST + lane * 4] = h4;
    }
  }
  // no barrier: wave-exclusive rows

  // ---- 4 layers: h = relu(h @ W + b), in-place per wave ----
#pragma unroll 1
  for (int layer = 0; layer < 4; ++layer) {
    // wave's 32 rows' fragments into registers (64 VGPRs)
    half8 hf[2][8];   // [mt][kk] : h[wrow0+mt*16+mi][kk*32+qi*8 .. +7]
#pragma unroll
    for (int mt = 0; mt < 2; ++mt)
#pragma unroll
      for (int kk = 0; kk < 8; ++kk)
        hf[mt][kk] = *(const half8*)&hlds[(wrow0 + mt * 16 + mi) * HST + kk * 32 + qi * 8];

    const half_t* wl = W + (size_t)layer * 65536;
    const float* bl = bias + layer * 256;
    half8 wA[8], wB[8];
    float4 bA, bB;
#pragma unroll
    for (int kk = 0; kk < 8; ++kk)
      wA[kk] = *(const half8*)&wl[(size_t)(kk * 16 + 0) * 512 + lane * 8];
    bA = *(const float4*)&bl[0 * 16 + qi * 4];

#pragma unroll
    for (int ntp = 0; ntp < 8; ++ntp) {
      int nt0 = ntp * 2;
      // prefetch nt0+1 while computing nt0
#pragma unroll
      for (int kk = 0; kk < 8; ++kk)
        wB[kk] = *(const half8*)&wl[(size_t)(kk * 16 + nt0 + 1) * 512 + lane * 8];
      bB = *(const float4*)&bl[(nt0 + 1) * 16 + qi * 4];
      {
        floatx4 acc0 = {bA.x, bA.y, bA.z, bA.w};
        floatx4 acc1 = {bA.x, bA.y, bA.z, bA.w};
#pragma unroll
        for (int kk = 0; kk < 8; ++kk) {
          acc0 = __builtin_amdgcn_mfma_f32_16x16x32_f16(wA[kk], hf[0][kk], acc0, 0, 0, 0);
          acc1 = __builtin_amdgcn_mfma_f32_16x16x32_f16(wA[kk], hf[1][kk], acc1, 0, 0, 0);
        }
        int colbase = nt0 * 16 + qi * 4;
        half4 h40, h41;
        h40[0] = (half_t)fmaxf(acc0[0], 0.f); h40[1] = (half_t)fmaxf(acc0[1], 0.f);
        h40[2] = (half_t)fmaxf(acc0[2], 0.f); h40[3] = (half_t)fmaxf(acc0[3], 0.f);
        h41[0] = (half_t)fmaxf(acc1[0], 0.f); h41[1] = (half_t)fmaxf(acc1[1], 0.f);
        h41[2] = (half_t)fmaxf(acc1[2], 0.f); h41[3] = (half_t)fmaxf(acc1[3], 0.f);
        *(half4*)&hlds[(wrow0 + mi) * HST + colbase] = h40;
        *(half4*)&hlds[(wrow0 + 16 + mi) * HST + colbase] = h41;
      }
      // prefetch nt0+2 while computing nt0+1
      if (ntp < 7) {
#pragma unroll
        for (int kk = 0; kk < 8; ++kk)
          wA[kk] = *(const half8*)&wl[(size_t)(kk * 16 + nt0 + 2) * 512 + lane * 8];
        bA = *(const float4*)&bl[(nt0 + 2) * 16 + qi * 4];
      }
      {
        floatx4 acc0 = {bB.x, bB.y, bB.z, bB.w};
        floatx4 acc1 = {bB.x, bB.y, bB.z, bB.w};
#pragma unroll
        for (int kk = 0; kk < 8; ++kk) {
          acc0 = __builtin_amdgcn_mfma_f32_16x16x32_f16(wB[kk], hf[0][kk], acc0, 0, 0, 0);
          acc1 = __builtin_amdgcn_mfma_f32_16x16x32_f16(wB[kk], hf[1][kk], acc1, 0, 0, 0);
        }
        int colbase = (nt0 + 1) * 16 + qi * 4;
        half4 h40, h41;
        h40[0] = (half_t)fmaxf(acc0[0], 0.f); h40[1] = (half_t)fmaxf(acc0[1], 0.f);
        h40[2] = (half_t)fmaxf(acc0[2], 0.f); h40[3] = (half_t)fmaxf(acc0[3], 0.f);
        h41[0] = (half_t)fmaxf(acc1[0], 0.f); h41[1] = (half_t)fmaxf(acc1[1], 0.f);
        h41[2] = (half_t)fmaxf(acc1[2], 0.f); h41[3] = (half_t)fmaxf(acc1[3], 0.f);
        *(half4*)&hlds[(wrow0 + mi) * HST + colbase] = h40;
        *(half4*)&hlds[(wrow0 + 16 + mi) * HST + colbase] = h41;
      }
    }
  }

  // ---- head: out = h . w + b2, per-mode epilogue. 2 lanes per row ----
  {
    int r = lane >> 1, hf2 = lane & 1;
    int rl = wrow0 + r;
    float sum = 0.f;
    const half_t* hrow = &hlds[rl * HST + hf2 * 128];
    const float* whp = wh + hf2 * 128;
#pragma unroll
    for (int j = 0; j < 16; ++j) {
      half8 hv = *(const half8*)&hrow[j * 8];
#pragma unroll
      for (int u = 0; u < 8; ++u) sum += (float)hv[u] * whp[j * 8 + u];
    }
    sum += __shfl_xor(sum, 1);
    if (hf2 == 0) {
      int row = brow0 + rl;
      float d = sum + b2p[0];
      if (mode == 0) {
        if (src_mask[row]) d = 0.f;
        float s2 = src_seq[(size_t)row * 3 + 2];
        outp[row] = (tanhf(d) + 1.0f) * s2;
      } else {
        int b = row >> 11;
        int m = row & (L_ - 1);
        float v = (m >= mlw[b]) ? 0.f : d;
        outp[row] = (mode == 1) ? fmaxf(v, 0.f) : v;
      }
    }
  }
}

extern "C" void kernel_launch(void* const* d_in, const int* in_sizes, int n_in,
                              void* d_out, int out_size, void* d_ws, size_t ws_size,
                              hipStream_t stream) {
  const float* x        = (const float*)d_in[0];
  const float* src_seq  = (const float*)d_in[1];
  const int*   durt     = (const int*)d_in[2];
  const float* pitcht   = (const float*)d_in[3];
  const float* energyt  = (const float*)d_in[4];
  const unsigned char* src_mask = (const unsigned char*)d_in[5];
  const float* dur_W  = (const float*)d_in[7];
  const float* dur_b  = (const float*)d_in[8];
  const float* dur_w  = (const float*)d_in[9];
  const float* dur_b2 = (const float*)d_in[10];
  const float* pit_W  = (const float*)d_in[11];
  const float* pit_b  = (const float*)d_in[12];
  const float* pit_w  = (const float*)d_in[13];
  const float* pit_b2 = (const float*)d_in[14];
  const float* en_W   = (const float*)d_in[15];
  const float* en_b   = (const float*)d_in[16];
  const float* en_w   = (const float*)d_in[17];
  const float* en_b2  = (const float*)d_in[18];
  const float* pemb   = (const float*)d_in[19];
  const float* eemb   = (const float*)d_in[20];

  float* out0 = (float*)d_out;              // [32,2048,256]
  float* out1 = out0 + 16777216;            // [32,512]   log_duration
  float* out2 = out1 + 16384;               // [32,2048]  pitch_prediction
  float* out3 = out2 + 65536;               // [32,2048]  energy_prediction
  float* out4 = out3 + 65536;               // [32]       mel_len (as float)
  float* out5 = out4 + 32;                  // [32,2048]  mel_mask (0/1 float)

  int* idx_ws = (int*)d_ws;                 // 65536 ints
  int* pi_ws  = idx_ws + 65536;             // 65536 ints
  int* ei_ws  = pi_ws + 65536;              // 65536 ints
  int* ml_ws  = ei_ws + 65536;              // 32 ints
  half_t* Wp  = (half_t*)((char*)d_ws + 786560);  // 786432 halves, 16B aligned

  prep_weights_kernel<<<dim3(384), dim3(256), 0, stream>>>(dur_W, pit_W, en_W, Wp);
  meta_kernel<<<dim3(128), dim3(256), 0, stream>>>(durt, pitcht, energyt,
                                                   idx_ws, pi_ws, ei_ws, ml_ws, out4, out5);
  out0_kernel<<<dim3(16384), dim3(256), 0, stream>>>(x, pemb, eemb,
                                                     idx_ws, pi_ws, ei_ws, ml_ws, out0);
  predictor_kernel<<<dim3(2304), dim3(128), 0, stream>>>(
      x, Wp,
      dur_b, dur_w, dur_b2,
      pit_b, pit_w, pit_b2,
      en_b, en_w, en_b2,
      idx_ws, ml_ws, src_seq, src_mask,
      out1, out2, out3);
}